// Round 6
// baseline (7533.089 us; speedup 1.0000x reference)
//
#include <hip/hip_runtime.h>
#include <hip/hip_bf16.h>
#include <float.h>

// Problem constants
#define BQ    64      // batch
#define CDIM  640     // channels (K)
#define LQ    441     // query descriptors per image
#define NCLS  32      // support classes
#define MS    2205    // support descriptors per class
#define ITILES 7      // 7*64 = 448 padded rows
#define JCHUNK 256    // j-chunk width
#define NJC    9      // 9*256 = 2304 padded cols
#define NKC    10     // 640/64 k-chunks
#define NEG_INF (-3.0e38f)

// A blob: per (b,it) row-major 64 rows x 640 k bf16 = 81920 B (5120 x 16B granules, 80/row)
#define ABYTES 81920
#define ADW    20480
// B blob: per (n,mc): [kc][ks][jf][lane] x 16B = 10*2*16*64*16 = 327680 B; per-kc chunk 32768 B
#define BMC    327680
#define BN     (NJC * BMC)   // 2,949,120 B per class

typedef __attribute__((ext_vector_type(8))) short short8;
typedef __attribute__((ext_vector_type(4))) float f32x4;

// sorted top-3 insert: a>=b>=c.  4 VALU ops via v_med3_f32.
__device__ __forceinline__ void ins3(float s, float& a, float& b, float& c) {
  float na = fmaxf(a, s);
  float nb = __builtin_amdgcn_fmed3f(a, b, s);
  c = fmaxf(c, fminf(b, s));
  a = na; b = nb;
}

// ================= split-prep path (used when workspace has ~410 KB headroom) =================

// norm_q: rnq_g[bx*64 + i] = 1/||x1[b,:,it*64+i]||  (448 blocks x 1024 thr)
__global__ __launch_bounds__(1024) void norm_q(const float* __restrict__ x1,
                                               float* __restrict__ rnq_g) {
  const int it = blockIdx.x, b = blockIdx.y;
  const int t = threadIdx.x;
  const int il = t & 63, cg = t >> 6;       // cg 0..15
  __shared__ float red[16][64];
  const int i = it * 64 + il;
  float ss = 0.f;
  if (i < LQ) {
    for (int c = cg; c < CDIM; c += 16) {
      float v = x1[((size_t)b * CDIM + c) * LQ + i];
      ss += v * v;
    }
  }
  red[cg][il] = ss;
  __syncthreads();
  if (t < 64) {
    float s = 0.f;
    #pragma unroll
    for (int g = 0; g < 16; ++g) s += red[g][t];
    rnq_g[(b * ITILES + it) * 64 + t] = (it * 64 + t < LQ) ? rsqrtf(s) : 0.f;
  }
}

// layout_q: one (bx, kc) slab -> 8 KB of A blob  (10 x 448 blocks x 256 thr)
__global__ __launch_bounds__(256) void layout_q(const float* __restrict__ x1,
                                                const float* __restrict__ rnq_g,
                                                unsigned short* __restrict__ Abf) {
  const int kc = blockIdx.x;     // 0..9
  const int bx = blockIdx.y;     // 0..447
  const int it = bx % ITILES, b = bx / ITILES;
  const int t = threadIdx.x;
  __shared__ unsigned short tile[64][66];
  __shared__ float rnq[64];
  if (t < 64) rnq[t] = rnq_g[bx * 64 + t];
  __syncthreads();
  for (int idx = t; idx < 4096; idx += 256) {
    int cc = idx >> 6, ii = idx & 63;
    int gi = it * 64 + ii;
    float v = 0.f;
    if (gi < LQ) v = x1[((size_t)b * CDIM + kc * 64 + cc) * LQ + gi] * rnq[ii];
    __hip_bfloat16 h = __float2bfloat16(v);
    tile[cc][ii] = *(unsigned short*)&h;
  }
  __syncthreads();
  unsigned int* blob = (unsigned int*)Abf + (size_t)bx * ADW;
  for (int idx = t; idx < 2048; idx += 256) {
    int row = idx >> 5, kp = idx & 31;
    unsigned int lo = tile[kp * 2][row], hi = tile[kp * 2 + 1][row];
    blob[row * 320 + kc * 32 + kp] = lo | (hi << 16);
  }
}

// norm_s: rns_g[n*2304 + mc*256 + j] = 1/||x2[n,:,mc*256+j]||  (9 x 32 blocks x 1024 thr)
__global__ __launch_bounds__(1024) void norm_s(const float* __restrict__ x2,
                                               float* __restrict__ rns_g) {
  const int mc = blockIdx.x, n = blockIdx.y;
  const int t = threadIdx.x;
  const int jj = t & 255, cg = t >> 8;      // cg 0..3
  __shared__ float red[4][256];
  const int j = mc * 256 + jj;
  float ss = 0.f;
  if (j < MS) {
    for (int c = cg; c < CDIM; c += 4) {
      float v = x2[((size_t)n * CDIM + c) * MS + j];
      ss += v * v;
    }
  }
  red[cg][jj] = ss;
  __syncthreads();
  if (t < 256) {
    float s = red[0][t] + red[1][t] + red[2][t] + red[3][t];
    rns_g[n * 2304 + mc * 256 + t] = (mc * 256 + t < MS) ? rsqrtf(s) : 0.f;
  }
}

// layout_s: one (kc, mc, n) slab -> 32 KB of B blob  (10 x 9 x 32 blocks x 512 thr)
__global__ __launch_bounds__(512) void layout_s(const float* __restrict__ x2,
                                                const float* __restrict__ rns_g,
                                                char* __restrict__ Bbf) {
  const int kc = blockIdx.x;     // 0..9
  const int mc = blockIdx.y;     // 0..8
  const int n  = blockIdx.z;     // 0..31
  const int t = threadIdx.x;
  __shared__ unsigned short tile[64][266];
  __shared__ float rns[256];
  if (t < 256) rns[t] = rns_g[n * 2304 + mc * 256 + t];
  __syncthreads();
  for (int idx = t; idx < 16384; idx += 512) {
    int cc = idx >> 8, jc = idx & 255;
    int gj = mc * 256 + jc;
    float v = 0.f;
    if (gj < MS) v = x2[((size_t)n * CDIM + kc * 64 + cc) * MS + gj] * rns[jc];
    __hip_bfloat16 h = __float2bfloat16(v);
    tile[cc][jc] = *(unsigned short*)&h;
  }
  __syncthreads();
  char* blob = Bbf + ((size_t)n * NJC + mc) * BMC + (size_t)kc * 32768;
  for (int g = t; g < 2048; g += 512) {
    int ks = g >> 10, jf = (g >> 6) & 15, ln = g & 63;
    int qq = ln >> 4, cl = ln & 15;
    int col = jf * 16 + cl, k0 = ks * 32 + qq * 8;
    unsigned int u0 = (unsigned int)tile[k0 + 0][col] | ((unsigned int)tile[k0 + 1][col] << 16);
    unsigned int u1 = (unsigned int)tile[k0 + 2][col] | ((unsigned int)tile[k0 + 3][col] << 16);
    unsigned int u2 = (unsigned int)tile[k0 + 4][col] | ((unsigned int)tile[k0 + 5][col] << 16);
    unsigned int u3 = (unsigned int)tile[k0 + 6][col] | ((unsigned int)tile[k0 + 7][col] << 16);
    int4 w; w.x = u0; w.y = u1; w.z = u2; w.w = u3;
    *(int4*)(blob + (size_t)g * 16) = w;
  }
}

// ================= fused-prep fallback (exact round-3 kernels) =================

__global__ __launch_bounds__(1024) void prep_q(const float* __restrict__ x1,
                                               unsigned short* __restrict__ Abf) {
  const int it = blockIdx.x;
  const int b  = blockIdx.y;
  const int t  = threadIdx.x;
  const int il = t & 63, cg = t >> 6;
  __shared__ float red[16][64];
  __shared__ float rnq[64];
  __shared__ unsigned short tile[64][66];
  const int i = it * 64 + il;
  float ss = 0.f;
  if (i < LQ) {
    for (int c = cg; c < CDIM; c += 16) {
      float v = x1[((size_t)b * CDIM + c) * LQ + i];
      ss += v * v;
    }
  }
  red[cg][il] = ss;
  __syncthreads();
  if (t < 64) {
    float s = 0.f;
    #pragma unroll
    for (int g = 0; g < 16; ++g) s += red[g][t];
    rnq[t] = (it * 64 + t < LQ) ? rsqrtf(s) : 0.f;
  }
  __syncthreads();
  unsigned int* blob = (unsigned int*)Abf + (size_t)(b * ITILES + it) * ADW;
  for (int kc = 0; kc < NKC; ++kc) {
    for (int idx = t; idx < 4096; idx += 1024) {
      int cc = idx >> 6, ii = idx & 63;
      int gi = it * 64 + ii;
      float v = 0.f;
      if (gi < LQ) v = x1[((size_t)b * CDIM + kc * 64 + cc) * LQ + gi] * rnq[ii];
      __hip_bfloat16 h = __float2bfloat16(v);
      tile[cc][ii] = *(unsigned short*)&h;
    }
    __syncthreads();
    for (int idx = t; idx < 2048; idx += 1024) {
      int row = idx >> 5, kp = idx & 31;
      unsigned int lo = tile[kp * 2][row], hi = tile[kp * 2 + 1][row];
      blob[row * 320 + kc * 32 + kp] = lo | (hi << 16);
    }
    __syncthreads();
  }
}

__global__ __launch_bounds__(1024) void prep_s(const float* __restrict__ x2,
                                               char* __restrict__ Bbf) {
  const int mc = blockIdx.x;
  const int n  = blockIdx.y;
  const int t  = threadIdx.x;
  const int jj = t & 255, cg = t >> 8;
  __shared__ float red[4][256];
  __shared__ float rns[256];
  __shared__ unsigned short tile[64][266];
  const int j = mc * 256 + jj;
  float ss = 0.f;
  if (j < MS) {
    for (int c = cg; c < CDIM; c += 4) {
      float v = x2[((size_t)n * CDIM + c) * MS + j];
      ss += v * v;
    }
  }
  red[cg][jj] = ss;
  __syncthreads();
  if (t < 256) {
    float s = red[0][t] + red[1][t] + red[2][t] + red[3][t];
    rns[t] = (mc * 256 + t < MS) ? rsqrtf(ss = s) : 0.f;
  }
  __syncthreads();
  char* blob = Bbf + ((size_t)n * NJC + mc) * BMC;
  for (int kc = 0; kc < NKC; ++kc) {
    for (int idx = t; idx < 16384; idx += 1024) {
      int cc = idx >> 8, jc = idx & 255;
      int gj = mc * 256 + jc;
      float v = 0.f;
      if (gj < MS) v = x2[((size_t)n * CDIM + kc * 64 + cc) * MS + gj] * rns[jc];
      __hip_bfloat16 h = __float2bfloat16(v);
      tile[cc][jc] = *(unsigned short*)&h;
    }
    __syncthreads();
    for (int g = t; g < 2048; g += 1024) {
      int ks = g >> 10, jf = (g >> 6) & 15, ln = g & 63;
      int qq = ln >> 4, cl = ln & 15;
      int col = jf * 16 + cl, k0 = ks * 32 + qq * 8;
      unsigned int u0 = (unsigned int)tile[k0 + 0][col] | ((unsigned int)tile[k0 + 1][col] << 16);
      unsigned int u1 = (unsigned int)tile[k0 + 2][col] | ((unsigned int)tile[k0 + 3][col] << 16);
      unsigned int u2 = (unsigned int)tile[k0 + 4][col] | ((unsigned int)tile[k0 + 5][col] << 16);
      unsigned int u3 = (unsigned int)tile[k0 + 6][col] | ((unsigned int)tile[k0 + 7][col] << 16);
      int4 w; w.x = u0; w.y = u1; w.z = u2; w.w = u3;
      *(int4*)(blob + (size_t)kc * 32768 + (size_t)g * 16) = w;
    }
    __syncthreads();
  }
}

// ---------------- main: 4-wave block, A in LDS (XOR-swizzled), B ping-pong from global ----------------
// Round-3 structure (2 blocks/CU, 2 waves/SIMD) -- the 12-wave variant spilled 280 B/thread.
// 1-D grid 14336. Decode for XCD L2 locality: xcd = bid&7 gets classes n = xcd*4 .. xcd*4+3.
__global__ __launch_bounds__(256, 2) void gemm_topk(const int4* __restrict__ Abf,
                                                    const char* __restrict__ Bbf,
                                                    float* __restrict__ out) {
  const int bid = blockIdx.x;
  const int xcd = bid & 7;
  const int s   = bid >> 3;              // 0..1791
  const int n   = xcd * 4 + s / 448;     // 4 classes per XCD
  const int bx  = s % 448;               // = b*7 + it
  const int b   = bx / 7;
  const int t    = threadIdx.x;
  const int lane = t & 63, wave = t >> 6;
  const int l15  = lane & 15, q = lane >> 4;

  __shared__ __align__(16) char smem[ABYTES];   // A tile; reused for merge

  // ---- stage A once, XOR-swizzled: granule (i,g) stored at i*80 + (g ^ (i&7)) ----
  {
    const int4* gA = Abf + (size_t)bx * 5120;
    int4* sA = (int4*)smem;
    #pragma unroll
    for (int rep = 0; rep < 20; ++rep) {
      int g0 = t + rep * 256;
      int i = g0 / 80;
      int g = g0 - i * 80;
      sA[i * 80 + (g ^ (i & 7))] = gA[g0];
    }
  }
  __syncthreads();

  float t3[16][3];
  #pragma unroll
  for (int r = 0; r < 16; ++r) { t3[r][0] = NEG_INF; t3[r][1] = NEG_INF; t3[r][2] = NEG_INF; }

  // A fragment addressing: byte = (r*16+l15)*1280 + kc*128 + oct*16, oct = (ks*4+q) ^ (l15&7)
  const int swz  = l15 & 7;
  const int oct0 = (q ^ swz) * 16;
  const int oct1 = ((4 + q) ^ swz) * 16;
  const char* Ab = smem + l15 * 1280;
  const int jb = wave * 64 + l15;        // per-lane column base within a j-chunk

  // B fragment base for this (n, wave, lane); blob walks contiguously in 32 KB k-chunks
  const char* BnB = Bbf + (size_t)n * BN + wave * 4096 + lane * 16;

  // ping-pong B buffers: no bcur<-bnxt copies (32 v_mov/kc saved vs round 3)
  short8 b0[2][4], b1[2][4];
  int off = 0;                            // offset of the chunk currently in b0
  #pragma unroll
  for (int ks = 0; ks < 2; ++ks)
    #pragma unroll
    for (int c = 0; c < 4; ++c)
      b0[ks][c] = *(const short8*)(BnB + ks * 16384 + c * 1024);

  for (int mc = 0; mc < NJC; ++mc) {
    f32x4 acc[4][4];
    #pragma unroll
    for (int r = 0; r < 4; ++r)
      #pragma unroll
      for (int c = 0; c < 4; ++c) acc[r][c] = (f32x4){0.f, 0.f, 0.f, 0.f};

    for (int kc2 = 0; kc2 < NKC; kc2 += 2) {
      // ---- even phase: prefetch b1, MFMA with b0 at kc2 ----
      int off1 = off + 32768; if (off1 == BN) off1 = 0;
      #pragma unroll
      for (int ks = 0; ks < 2; ++ks)
        #pragma unroll
        for (int c = 0; c < 4; ++c)
          b1[ks][c] = *(const short8*)(BnB + off1 + ks * 16384 + c * 1024);

      __builtin_amdgcn_s_setprio(1);
      #pragma unroll
      for (int ks = 0; ks < 2; ++ks) {
        const int oct = ks ? oct1 : oct0;
        short8 af[4];
        #pragma unroll
        for (int r = 0; r < 4; ++r)
          af[r] = *(const short8*)(Ab + r * 20480 + kc2 * 128 + oct);
        #pragma unroll
        for (int r = 0; r < 4; ++r)
          #pragma unroll
          for (int c = 0; c < 4; ++c)
            acc[r][c] = __builtin_amdgcn_mfma_f32_16x16x32_bf16(af[r], b0[ks][c], acc[r][c], 0, 0, 0);
      }
      __builtin_amdgcn_s_setprio(0);

      // ---- odd phase: prefetch b0, MFMA with b1 at kc2+1 ----
      int off2 = off1 + 32768; if (off2 == BN) off2 = 0;
      #pragma unroll
      for (int ks = 0; ks < 2; ++ks)
        #pragma unroll
        for (int c = 0; c < 4; ++c)
          b0[ks][c] = *(const short8*)(BnB + off2 + ks * 16384 + c * 1024);

      __builtin_amdgcn_s_setprio(1);
      #pragma unroll
      for (int ks = 0; ks < 2; ++ks) {
        const int oct = ks ? oct1 : oct0;
        short8 af[4];
        #pragma unroll
        for (int r = 0; r < 4; ++r)
          af[r] = *(const short8*)(Ab + r * 20480 + (kc2 + 1) * 128 + oct);
        #pragma unroll
        for (int r = 0; r < 4; ++r)
          #pragma unroll
          for (int c = 0; c < 4; ++c)
            acc[r][c] = __builtin_amdgcn_mfma_f32_16x16x32_bf16(af[r], b1[ks][c], acc[r][c], 0, 0, 0);
      }
      __builtin_amdgcn_s_setprio(0);

      off = off2;
    }

    // fold this 256-col chunk into running top-3 (uniform mask: single body, no spill)
    #pragma unroll
    for (int c = 0; c < 4; ++c) {
      const bool jv = (mc * JCHUNK + c * 16 + jb) < MS;
      #pragma unroll
      for (int r = 0; r < 4; ++r)
        #pragma unroll
        for (int reg = 0; reg < 4; ++reg) {
          float sv = jv ? acc[r][c][reg] : NEG_INF;
          ins3(sv, t3[r * 4 + reg][0], t3[r * 4 + reg][1], t3[r * 4 + reg][2]);
        }
    }
  }

  // ---- merge per-lane top-3 across the 64 lanes holding each row ----
  // mrg row stride 65 slots: 16 rows spread over 16 banks (stride-64 was a 32-way conflict).
  __syncthreads();                          // all waves done reading A; reuse smem
  float* mrg = (float*)smem;                // 64 rows * 65 slots * 3 = 49920 B
  float* aux = (float*)(smem + 49920);      // 64 rows * 4 segs * 3 = 3072 B
  #pragma unroll
  for (int r = 0; r < 4; ++r)
    #pragma unroll
    for (int reg = 0; reg < 4; ++reg) {
      int row = r * 16 + q * 4 + reg;       // C/D layout: row = quad*4 + reg
      int col = wave * 16 + l15;            // storage slot only
      float* p = &mrg[(row * 65 + col) * 3];
      p[0] = t3[r * 4 + reg][0]; p[1] = t3[r * 4 + reg][1]; p[2] = t3[r * 4 + reg][2];
    }
  __syncthreads();
  {
    int row = t >> 2, seg = t & 3;
    float a = NEG_INF, bb = NEG_INF, cc = NEG_INF;
    for (int c0 = seg * 16; c0 < seg * 16 + 16; ++c0) {
      const float* p = &mrg[(row * 65 + c0) * 3];
      ins3(p[0], a, bb, cc); ins3(p[1], a, bb, cc); ins3(p[2], a, bb, cc);
    }
    aux[(row * 4 + seg) * 3 + 0] = a;
    aux[(row * 4 + seg) * 3 + 1] = bb;
    aux[(row * 4 + seg) * 3 + 2] = cc;
  }
  __syncthreads();
  if (t < 64) {
    float a = NEG_INF, bb = NEG_INF, cc = NEG_INF;
    for (int v = 0; v < 12; ++v) ins3(aux[t * 12 + v], a, bb, cc);
    float sum = a + bb + cc;                // padded rows contribute exactly 0
    for (int offr = 32; offr > 0; offr >>= 1) sum += __shfl_down(sum, offr);
    if (t == 0) atomicAdd(&out[b * NCLS + n], sum);
  }
}

extern "C" void kernel_launch(void* const* d_in, const int* in_sizes, int n_in,
                              void* d_out, int out_size, void* d_ws, size_t ws_size,
                              hipStream_t stream) {
  const float* x1 = (const float*)d_in[0];   // [64, 640, 441] fp32
  const float* x2 = (const float*)d_in[1];   // [32, 640, 2205] fp32
  float* out = (float*)d_out;                // [64, 32] fp32

  // workspace: Abf 36,700,160 B | Bbf 94,371,840 B | (optional) rnq 114,688 B | rns 294,912 B
  const size_t abytes_tot = (size_t)BQ * ITILES * ABYTES;
  const size_t bbytes_tot = (size_t)NCLS * BN;
  unsigned short* Abf = (unsigned short*)d_ws;
  char* Bbf = (char*)d_ws + abytes_tot;
  float* rnq_g = (float*)((char*)d_ws + abytes_tot + bbytes_tot);
  float* rns_g = rnq_g + BQ * ITILES * 64;
  const size_t need_split = abytes_tot + bbytes_tot
                          + (size_t)(BQ * ITILES * 64 + NCLS * 2304) * sizeof(float);

  hipMemsetAsync(d_out, 0, BQ * NCLS * sizeof(float), stream);
  if (ws_size >= need_split) {
    norm_q<<<dim3(ITILES, BQ), 1024, 0, stream>>>(x1, rnq_g);
    norm_s<<<dim3(NJC, NCLS), 1024, 0, stream>>>(x2, rns_g);
    layout_q<<<dim3(NKC, BQ * ITILES), 256, 0, stream>>>(x1, rnq_g, Abf);
    layout_s<<<dim3(NKC, NJC, NCLS), 512, 0, stream>>>(x2, rns_g, Bbf);
  } else {
    prep_q<<<dim3(ITILES, BQ), 1024, 0, stream>>>(x1, Abf);
    prep_s<<<dim3(NJC, NCLS), 1024, 0, stream>>>(x2, Bbf);
  }
  gemm_topk<<<BQ * ITILES * NCLS, 256, 0, stream>>>((const int4*)Abf, Bbf, out);
}

// Round 7
// 2647.654 us; speedup vs baseline: 2.8452x; 2.8452x over previous
//
#include <hip/hip_runtime.h>
#include <hip/hip_bf16.h>
#include <float.h>

// Problem constants
#define BQ    64      // batch
#define CDIM  640     // channels (K)
#define LQ    441     // query descriptors per image
#define NCLS  32      // support classes
#define MS    2205    // support descriptors per class
#define ITILES 7      // 7*64 = 448 padded rows
#define JCHUNK 256    // j-chunk width
#define NJC    9      // 9*256 = 2304 padded cols
#define NKC    10     // 640/64 k-chunks
#define NEG_INF (-3.0e38f)

// A blob: per (b,it) row-major 64 rows x 640 k bf16 = 81920 B (5120 x 16B granules, 80/row)
#define ABYTES 81920
#define ADW    20480
// B blob: per (n,mc): [kc][ks][jf][lane] x 16B = 10*2*16*64*16 = 327680 B; per-kc chunk 32768 B
#define BMC    327680
#define BN     (NJC * BMC)   // 2,949,120 B per class

typedef __attribute__((ext_vector_type(8))) short short8;
typedef __attribute__((ext_vector_type(4))) float f32x4;

// sorted top-3 insert: a>=b>=c.  4 VALU ops via v_med3_f32.
__device__ __forceinline__ void ins3(float s, float& a, float& b, float& c) {
  float na = fmaxf(a, s);
  float nb = __builtin_amdgcn_fmed3f(a, b, s);
  c = fmaxf(c, fminf(b, s));
  a = na; b = nb;
}

// ================= split-prep path (proven round 6: prep gap 400 -> ~40 us) =================

// norm_q: rnq_g[bx*64 + i] = 1/||x1[b,:,it*64+i]||  (448 blocks x 1024 thr)
__global__ __launch_bounds__(1024) void norm_q(const float* __restrict__ x1,
                                               float* __restrict__ rnq_g) {
  const int it = blockIdx.x, b = blockIdx.y;
  const int t = threadIdx.x;
  const int il = t & 63, cg = t >> 6;       // cg 0..15
  __shared__ float red[16][64];
  const int i = it * 64 + il;
  float ss = 0.f;
  if (i < LQ) {
    for (int c = cg; c < CDIM; c += 16) {
      float v = x1[((size_t)b * CDIM + c) * LQ + i];
      ss += v * v;
    }
  }
  red[cg][il] = ss;
  __syncthreads();
  if (t < 64) {
    float s = 0.f;
    #pragma unroll
    for (int g = 0; g < 16; ++g) s += red[g][t];
    rnq_g[(b * ITILES + it) * 64 + t] = (it * 64 + t < LQ) ? rsqrtf(s) : 0.f;
  }
}

// layout_q: one (bx, kc) slab -> 8 KB of A blob  (10 x 448 blocks x 256 thr)
__global__ __launch_bounds__(256) void layout_q(const float* __restrict__ x1,
                                                const float* __restrict__ rnq_g,
                                                unsigned short* __restrict__ Abf) {
  const int kc = blockIdx.x;     // 0..9
  const int bx = blockIdx.y;     // 0..447
  const int it = bx % ITILES, b = bx / ITILES;
  const int t = threadIdx.x;
  __shared__ unsigned short tile[64][66];
  __shared__ float rnq[64];
  if (t < 64) rnq[t] = rnq_g[bx * 64 + t];
  __syncthreads();
  for (int idx = t; idx < 4096; idx += 256) {
    int cc = idx >> 6, ii = idx & 63;
    int gi = it * 64 + ii;
    float v = 0.f;
    if (gi < LQ) v = x1[((size_t)b * CDIM + kc * 64 + cc) * LQ + gi] * rnq[ii];
    __hip_bfloat16 h = __float2bfloat16(v);
    tile[cc][ii] = *(unsigned short*)&h;
  }
  __syncthreads();
  unsigned int* blob = (unsigned int*)Abf + (size_t)bx * ADW;
  for (int idx = t; idx < 2048; idx += 256) {
    int row = idx >> 5, kp = idx & 31;
    unsigned int lo = tile[kp * 2][row], hi = tile[kp * 2 + 1][row];
    blob[row * 320 + kc * 32 + kp] = lo | (hi << 16);
  }
}

// norm_s: rns_g[n*2304 + mc*256 + j] = 1/||x2[n,:,mc*256+j]||  (9 x 32 blocks x 1024 thr)
__global__ __launch_bounds__(1024) void norm_s(const float* __restrict__ x2,
                                               float* __restrict__ rns_g) {
  const int mc = blockIdx.x, n = blockIdx.y;
  const int t = threadIdx.x;
  const int jj = t & 255, cg = t >> 8;      // cg 0..3
  __shared__ float red[4][256];
  const int j = mc * 256 + jj;
  float ss = 0.f;
  if (j < MS) {
    for (int c = cg; c < CDIM; c += 4) {
      float v = x2[((size_t)n * CDIM + c) * MS + j];
      ss += v * v;
    }
  }
  red[cg][jj] = ss;
  __syncthreads();
  if (t < 256) {
    float s = red[0][t] + red[1][t] + red[2][t] + red[3][t];
    rns_g[n * 2304 + mc * 256 + t] = (mc * 256 + t < MS) ? rsqrtf(s) : 0.f;
  }
}

// layout_s: one (kc, mc, n) slab -> 32 KB of B blob  (10 x 9 x 32 blocks x 512 thr)
__global__ __launch_bounds__(512) void layout_s(const float* __restrict__ x2,
                                                const float* __restrict__ rns_g,
                                                char* __restrict__ Bbf) {
  const int kc = blockIdx.x;     // 0..9
  const int mc = blockIdx.y;     // 0..8
  const int n  = blockIdx.z;     // 0..31
  const int t = threadIdx.x;
  __shared__ unsigned short tile[64][266];
  __shared__ float rns[256];
  if (t < 256) rns[t] = rns_g[n * 2304 + mc * 256 + t];
  __syncthreads();
  for (int idx = t; idx < 16384; idx += 512) {
    int cc = idx >> 8, jc = idx & 255;
    int gj = mc * 256 + jc;
    float v = 0.f;
    if (gj < MS) v = x2[((size_t)n * CDIM + kc * 64 + cc) * MS + gj] * rns[jc];
    __hip_bfloat16 h = __float2bfloat16(v);
    tile[cc][jc] = *(unsigned short*)&h;
  }
  __syncthreads();
  char* blob = Bbf + ((size_t)n * NJC + mc) * BMC + (size_t)kc * 32768;
  for (int g = t; g < 2048; g += 512) {
    int ks = g >> 10, jf = (g >> 6) & 15, ln = g & 63;
    int qq = ln >> 4, cl = ln & 15;
    int col = jf * 16 + cl, k0 = ks * 32 + qq * 8;
    unsigned int u0 = (unsigned int)tile[k0 + 0][col] | ((unsigned int)tile[k0 + 1][col] << 16);
    unsigned int u1 = (unsigned int)tile[k0 + 2][col] | ((unsigned int)tile[k0 + 3][col] << 16);
    unsigned int u2 = (unsigned int)tile[k0 + 4][col] | ((unsigned int)tile[k0 + 5][col] << 16);
    unsigned int u3 = (unsigned int)tile[k0 + 6][col] | ((unsigned int)tile[k0 + 7][col] << 16);
    int4 w; w.x = u0; w.y = u1; w.z = u2; w.w = u3;
    *(int4*)(blob + (size_t)g * 16) = w;
  }
}

// ================= fused-prep fallback =================

__global__ __launch_bounds__(1024) void prep_q(const float* __restrict__ x1,
                                               unsigned short* __restrict__ Abf) {
  const int it = blockIdx.x;
  const int b  = blockIdx.y;
  const int t  = threadIdx.x;
  const int il = t & 63, cg = t >> 6;
  __shared__ float red[16][64];
  __shared__ float rnq[64];
  __shared__ unsigned short tile[64][66];
  const int i = it * 64 + il;
  float ss = 0.f;
  if (i < LQ) {
    for (int c = cg; c < CDIM; c += 16) {
      float v = x1[((size_t)b * CDIM + c) * LQ + i];
      ss += v * v;
    }
  }
  red[cg][il] = ss;
  __syncthreads();
  if (t < 64) {
    float s = 0.f;
    #pragma unroll
    for (int g = 0; g < 16; ++g) s += red[g][t];
    rnq[t] = (it * 64 + t < LQ) ? rsqrtf(s) : 0.f;
  }
  __syncthreads();
  unsigned int* blob = (unsigned int*)Abf + (size_t)(b * ITILES + it) * ADW;
  for (int kc = 0; kc < NKC; ++kc) {
    for (int idx = t; idx < 4096; idx += 1024) {
      int cc = idx >> 6, ii = idx & 63;
      int gi = it * 64 + ii;
      float v = 0.f;
      if (gi < LQ) v = x1[((size_t)b * CDIM + kc * 64 + cc) * LQ + gi] * rnq[ii];
      __hip_bfloat16 h = __float2bfloat16(v);
      tile[cc][ii] = *(unsigned short*)&h;
    }
    __syncthreads();
    for (int idx = t; idx < 2048; idx += 1024) {
      int row = idx >> 5, kp = idx & 31;
      unsigned int lo = tile[kp * 2][row], hi = tile[kp * 2 + 1][row];
      blob[row * 320 + kc * 32 + kp] = lo | (hi << 16);
    }
    __syncthreads();
  }
}

__global__ __launch_bounds__(1024) void prep_s(const float* __restrict__ x2,
                                               char* __restrict__ Bbf) {
  const int mc = blockIdx.x;
  const int n  = blockIdx.y;
  const int t  = threadIdx.x;
  const int jj = t & 255, cg = t >> 8;
  __shared__ float red[4][256];
  __shared__ float rns[256];
  __shared__ unsigned short tile[64][266];
  const int j = mc * 256 + jj;
  float ss = 0.f;
  if (j < MS) {
    for (int c = cg; c < CDIM; c += 4) {
      float v = x2[((size_t)n * CDIM + c) * MS + j];
      ss += v * v;
    }
  }
  red[cg][jj] = ss;
  __syncthreads();
  if (t < 256) {
    float s = red[0][t] + red[1][t] + red[2][t] + red[3][t];
    rns[t] = (mc * 256 + t < MS) ? rsqrtf(s) : 0.f;
  }
  __syncthreads();
  char* blob = Bbf + ((size_t)n * NJC + mc) * BMC;
  for (int kc = 0; kc < NKC; ++kc) {
    for (int idx = t; idx < 16384; idx += 1024) {
      int cc = idx >> 8, jc = idx & 255;
      int gj = mc * 256 + jc;
      float v = 0.f;
      if (gj < MS) v = x2[((size_t)n * CDIM + kc * 64 + cc) * MS + gj] * rns[jc];
      __hip_bfloat16 h = __float2bfloat16(v);
      tile[cc][jc] = *(unsigned short*)&h;
    }
    __syncthreads();
    for (int g = t; g < 2048; g += 1024) {
      int ks = g >> 10, jf = (g >> 6) & 15, ln = g & 63;
      int qq = ln >> 4, cl = ln & 15;
      int col = jf * 16 + cl, k0 = ks * 32 + qq * 8;
      unsigned int u0 = (unsigned int)tile[k0 + 0][col] | ((unsigned int)tile[k0 + 1][col] << 16);
      unsigned int u1 = (unsigned int)tile[k0 + 2][col] | ((unsigned int)tile[k0 + 3][col] << 16);
      unsigned int u2 = (unsigned int)tile[k0 + 4][col] | ((unsigned int)tile[k0 + 5][col] << 16);
      unsigned int u3 = (unsigned int)tile[k0 + 6][col] | ((unsigned int)tile[k0 + 7][col] << 16);
      int4 w; w.x = u0; w.y = u1; w.z = u2; w.w = u3;
      *(int4*)(blob + (size_t)kc * 32768 + (size_t)g * 16) = w;
    }
    __syncthreads();
  }
}

// ---------------- main: EXACT round-3 K-loop (bcur/bnxt + copies). ----------------
// PITFALL (round 6): replacing the copies with a b0/b1 register ping-pong exploded
// HBM FETCH 1.13 GB -> 18.3 GB (L3 hit collapse) and ran 3.3x slower. Do not retry
// without disasm evidence.  1-D grid 14336; xcd = bid&7 gets classes n = xcd*4..+3.
__global__ __launch_bounds__(256, 2) void gemm_topk(const int4* __restrict__ Abf,
                                                    const char* __restrict__ Bbf,
                                                    float* __restrict__ out) {
  const int bid = blockIdx.x;
  const int xcd = bid & 7;
  const int s   = bid >> 3;              // 0..1791
  const int n   = xcd * 4 + s / 448;     // 4 classes per XCD
  const int bx  = s % 448;               // = b*7 + it
  const int b   = bx / 7;
  const int t    = threadIdx.x;
  const int lane = t & 63, wave = t >> 6;
  const int l15  = lane & 15, q = lane >> 4;

  __shared__ __align__(16) char smem[ABYTES];   // A tile; reused for merge

  // ---- stage A once, XOR-swizzled: granule (i,g) stored at i*80 + (g ^ (i&7)) ----
  {
    const int4* gA = Abf + (size_t)bx * 5120;
    int4* sA = (int4*)smem;
    #pragma unroll
    for (int rep = 0; rep < 20; ++rep) {
      int g0 = t + rep * 256;
      int i = g0 / 80;
      int g = g0 - i * 80;
      sA[i * 80 + (g ^ (i & 7))] = gA[g0];
    }
  }
  __syncthreads();

  float t3[16][3];
  #pragma unroll
  for (int r = 0; r < 16; ++r) { t3[r][0] = NEG_INF; t3[r][1] = NEG_INF; t3[r][2] = NEG_INF; }

  // A fragment addressing: byte = (r*16+l15)*1280 + kc*128 + oct*16, oct = (ks*4+q) ^ (l15&7)
  const int swz  = l15 & 7;
  const int oct0 = (q ^ swz) * 16;
  const int oct1 = ((4 + q) ^ swz) * 16;
  const char* Ab = smem + l15 * 1280;
  const int jb = wave * 64 + l15;        // per-lane column base within a j-chunk

  // B fragment base for this (n, wave, lane); blob walks contiguously in 32 KB k-chunks
  const char* BnB = Bbf + (size_t)n * BN + wave * 4096 + lane * 16;

  short8 bcur[2][4], bnxt[2][4];
  int off = 0;
  #pragma unroll
  for (int ks = 0; ks < 2; ++ks)
    #pragma unroll
    for (int c = 0; c < 4; ++c)
      bcur[ks][c] = *(const short8*)(BnB + ks * 16384 + c * 1024);

  for (int mc = 0; mc < NJC; ++mc) {
    f32x4 acc[4][4];
    #pragma unroll
    for (int r = 0; r < 4; ++r)
      #pragma unroll
      for (int c = 0; c < 4; ++c) acc[r][c] = (f32x4){0.f, 0.f, 0.f, 0.f};

    #pragma unroll 2
    for (int kc = 0; kc < NKC; ++kc) {
      int offn = off + 32768;
      if (offn == BN) offn = 0;              // wrap: harmless re-read of class start
      #pragma unroll
      for (int ks = 0; ks < 2; ++ks)
        #pragma unroll
        for (int c = 0; c < 4; ++c)
          bnxt[ks][c] = *(const short8*)(BnB + offn + ks * 16384 + c * 1024);

      __builtin_amdgcn_s_setprio(1);         // favor the MFMA-phase wave on this SIMD
      #pragma unroll
      for (int ks = 0; ks < 2; ++ks) {
        const int oct = ks ? oct1 : oct0;
        short8 af[4];
        #pragma unroll
        for (int r = 0; r < 4; ++r)
          af[r] = *(const short8*)(Ab + r * 20480 + kc * 128 + oct);
        #pragma unroll
        for (int r = 0; r < 4; ++r)
          #pragma unroll
          for (int c = 0; c < 4; ++c)
            acc[r][c] = __builtin_amdgcn_mfma_f32_16x16x32_bf16(af[r], bcur[ks][c], acc[r][c], 0, 0, 0);
      }
      __builtin_amdgcn_s_setprio(0);

      #pragma unroll
      for (int ks = 0; ks < 2; ++ks)
        #pragma unroll
        for (int c = 0; c < 4; ++c) bcur[ks][c] = bnxt[ks][c];
      off = offn;
    }

    // fold this 256-col chunk into running top-3 (uniform mask: single body, no spill)
    #pragma unroll
    for (int c = 0; c < 4; ++c) {
      const bool jv = (mc * JCHUNK + c * 16 + jb) < MS;
      #pragma unroll
      for (int r = 0; r < 4; ++r)
        #pragma unroll
        for (int reg = 0; reg < 4; ++reg) {
          float sv = jv ? acc[r][c][reg] : NEG_INF;
          ins3(sv, t3[r * 4 + reg][0], t3[r * 4 + reg][1], t3[r * 4 + reg][2]);
        }
    }
  }

  // ---- merge per-lane top-3 across the 64 lanes holding each row ----
  // mrg row stride 65 slots: 16 rows spread over 16 banks (stride-64 was a 32-way conflict).
  __syncthreads();                          // all waves done reading A; reuse smem
  float* mrg = (float*)smem;                // 64 rows * 65 slots * 3 = 49920 B
  float* aux = (float*)(smem + 49920);      // 64 rows * 4 segs * 3 = 3072 B
  #pragma unroll
  for (int r = 0; r < 4; ++r)
    #pragma unroll
    for (int reg = 0; reg < 4; ++reg) {
      int row = r * 16 + q * 4 + reg;       // C/D layout: row = quad*4 + reg
      int col = wave * 16 + l15;            // storage slot only
      float* p = &mrg[(row * 65 + col) * 3];
      p[0] = t3[r * 4 + reg][0]; p[1] = t3[r * 4 + reg][1]; p[2] = t3[r * 4 + reg][2];
    }
  __syncthreads();
  {
    int row = t >> 2, seg = t & 3;
    float a = NEG_INF, bb = NEG_INF, cc = NEG_INF;
    for (int c0 = seg * 16; c0 < seg * 16 + 16; ++c0) {
      const float* p = &mrg[(row * 65 + c0) * 3];
      ins3(p[0], a, bb, cc); ins3(p[1], a, bb, cc); ins3(p[2], a, bb, cc);
    }
    aux[(row * 4 + seg) * 3 + 0] = a;
    aux[(row * 4 + seg) * 3 + 1] = bb;
    aux[(row * 4 + seg) * 3 + 2] = cc;
  }
  __syncthreads();
  if (t < 64) {
    float a = NEG_INF, bb = NEG_INF, cc = NEG_INF;
    for (int v = 0; v < 12; ++v) ins3(aux[t * 12 + v], a, bb, cc);
    float sum = a + bb + cc;                // padded rows contribute exactly 0
    for (int offr = 32; offr > 0; offr >>= 1) sum += __shfl_down(sum, offr);
    if (t == 0) atomicAdd(&out[b * NCLS + n], sum);
  }
}

extern "C" void kernel_launch(void* const* d_in, const int* in_sizes, int n_in,
                              void* d_out, int out_size, void* d_ws, size_t ws_size,
                              hipStream_t stream) {
  const float* x1 = (const float*)d_in[0];   // [64, 640, 441] fp32
  const float* x2 = (const float*)d_in[1];   // [32, 640, 2205] fp32
  float* out = (float*)d_out;                // [64, 32] fp32

  // workspace: Abf 36,700,160 B | Bbf 94,371,840 B | (optional) rnq 114,688 B | rns 294,912 B
  const size_t abytes_tot = (size_t)BQ * ITILES * ABYTES;
  const size_t bbytes_tot = (size_t)NCLS * BN;
  unsigned short* Abf = (unsigned short*)d_ws;
  char* Bbf = (char*)d_ws + abytes_tot;
  float* rnq_g = (float*)((char*)d_ws + abytes_tot + bbytes_tot);
  float* rns_g = rnq_g + BQ * ITILES * 64;
  const size_t need_split = abytes_tot + bbytes_tot
                          + (size_t)(BQ * ITILES * 64 + NCLS * 2304) * sizeof(float);

  hipMemsetAsync(d_out, 0, BQ * NCLS * sizeof(float), stream);
  if (ws_size >= need_split) {
    norm_q<<<dim3(ITILES, BQ), 1024, 0, stream>>>(x1, rnq_g);
    norm_s<<<dim3(NJC, NCLS), 1024, 0, stream>>>(x2, rns_g);
    layout_q<<<dim3(NKC, BQ * ITILES), 256, 0, stream>>>(x1, rnq_g, Abf);
    layout_s<<<dim3(NKC, NJC, NCLS), 512, 0, stream>>>(x2, rns_g, Bbf);
  } else {
    prep_q<<<dim3(ITILES, BQ), 1024, 0, stream>>>(x1, Abf);
    prep_s<<<dim3(NJC, NCLS), 1024, 0, stream>>>(x2, Bbf);
  }
  gemm_topk<<<BQ * ITILES * NCLS, 256, 0, stream>>>((const int4*)Abf, Bbf, out);
}